// Round 1
// baseline (238.097 us; speedup 1.0000x reference)
//
#include <hip/hip_runtime.h>

// bMomentumLIF forward: x[B,T,F] fp32 -> spikes[B,T,F] fp32
// Recurrence per neuron (b,f) over t:
//   u  = u_last * 0.5 + x[t]            (TAU=2, /2 == *0.5 exactly)
//   s  = (u - th >= 0) ? 1 : 0
//   m  = mt*m + (1-mt)*(u - u_last)
//   u' = (u*lb + m*(1-lb)) * (1-s)
// Memory-bound target: 128 MiB in + 128 MiB out -> ~43 us floor @ 6.3 TB/s.
//
// R1 restructure: the previous version fully unrolled the T=64 loop with
// float4 per thread (512 blocks / 2048 waves). LLVM hoists the 64 affine
// loads until VGPRs are exhausted -> spills / 1-wave-per-SIMD occupancy,
// defeating latency hiding (achieved only 1.14 TB/s). This version:
//   * float2 per thread -> 1024 blocks = 4096 waves = 16 waves/CU
//   * #pragma unroll 2 (forbid full unroll)
//   * explicit 2-deep load pipeline (x[t+1], x[t+2] in flight)
//   * __launch_bounds__(256, 4) caps VGPR at 128 (actual ~30)

constexpr int B  = 64;
constexpr int T  = 64;
constexpr int F  = 8192;
constexpr int F2 = F / 2;   // float2 granularity along F

__global__ __launch_bounds__(256, 4) void lif_fwd_kernel(
    const float2* __restrict__ x,
    const float*  __restrict__ momentum,
    const float*  __restrict__ lamb,
    const float*  __restrict__ thresholds,
    float2*       __restrict__ out)
{
    // Disable FMA contraction: spike threshold is exact-compare against the
    // numpy fp32 reference; contraction changes rounding of the m-update and
    // can flip spikes at the boundary (error 1.0).
#pragma clang fp contract(off)

    const int tid = blockIdx.x * blockDim.x + threadIdx.x;   // 0 .. B*F2-1
    const int b   = tid >> 12;            // tid / F2   (F2 == 4096)
    const int f2  = tid & (F2 - 1);

    const float mt  = momentum[0];
    const float omt = 1.0f - mt;
    const float lb  = lamb[0];
    const float olb = 1.0f - lb;
    const float th  = thresholds[0];

    int idx = b * (T * F2) + f2;   // float2 index; stride F2 per timestep

    float u0 = 0.0f, u1 = 0.0f;
    float m0 = 0.0f, m1 = 0.0f;

    // 2-deep software pipeline: keep loads for t+1 and t+2 in flight.
    float2 x0 = x[idx];            // t = 0
    float2 x1 = x[idx + F2];       // t = 1   (T >= 2 always)

#pragma unroll 2
    for (int t = 0; t < T; ++t) {
        // Prefetch t+2 (clamped to current idx on the tail; value discarded).
        const int poff = (t + 2 < T) ? 2 * F2 : 0;
        const float2 xn = x[idx + poff];

        float2 sv;

        // component 0
        {
            const float u  = u0 * 0.5f + x0.x;
            const float s  = ((u - th) >= 0.0f) ? 1.0f : 0.0f;
            const float a  = mt * m0;
            const float bq = omt * (u - u0);
            m0 = a + bq;
            u0 = (u * lb + m0 * olb) * (1.0f - s);
            sv.x = s;
        }
        // component 1
        {
            const float u  = u1 * 0.5f + x0.y;
            const float s  = ((u - th) >= 0.0f) ? 1.0f : 0.0f;
            const float a  = mt * m1;
            const float bq = omt * (u - u1);
            m1 = a + bq;
            u1 = (u * lb + m1 * olb) * (1.0f - s);
            sv.y = s;
        }

        out[idx] = sv;
        idx += F2;
        x0 = x1;
        x1 = xn;
    }
}

extern "C" void kernel_launch(void* const* d_in, const int* in_sizes, int n_in,
                              void* d_out, int out_size, void* d_ws, size_t ws_size,
                              hipStream_t stream) {
    const float2* x   = (const float2*)d_in[0];
    const float*  mom = (const float*)d_in[1];
    const float*  lmb = (const float*)d_in[2];
    const float*  thr = (const float*)d_in[3];
    float2* out = (float2*)d_out;

    const int n_threads = B * F2;          // 262144
    const int block = 256;
    const int grid = n_threads / block;    // 1024
    lif_fwd_kernel<<<grid, block, 0, stream>>>(x, mom, lmb, thr, out);
}

// Round 3
// 226.620 us; speedup vs baseline: 1.0506x; 1.0506x over previous
//
#include <hip/hip_runtime.h>

// bMomentumLIF forward: x[B,T,F] fp32 -> spikes[B,T,F] fp32
// Recurrence per neuron (b,f) over t:
//   u  = u_last * 0.5 + x[t]            (TAU=2, /2 == *0.5 exactly)
//   s  = (u - th >= 0) ? 1 : 0
//   m  = mt*m + (1-mt)*(u - u_last)
//   u' = (u*lb + m*(1-lb)) * (1-s)
//
// R3 = R2 with the compile fix: __builtin_nontemporal_* requires a true
// clang vector type, not HIP_vector_type. Use ext_vector_type(4).
//
// Evidence so far: R0 (float4, full unroll) and R1 (float2, pipelined,
// 2x waves) time identically (235.6 vs 238.1 us) and the lif dispatch
// never makes the top-5 rocprof table (all ~81us fillBuffer resets) ->
// kernel itself <80us; dur_us dominated by harness fills. Floor for
// 268MB R+W at demonstrated 6.6 TB/s ~ 41us. Last shared candidate
// limiter: cache allocation on zero-reuse streams -> nontemporal (nt).

constexpr int B  = 64;
constexpr int T  = 64;
constexpr int F  = 8192;
constexpr int F4 = F / 4;   // float4 granularity along F (2048)

typedef float fvec4 __attribute__((ext_vector_type(4)));

__global__ __launch_bounds__(256) void lif_fwd_kernel(
    const fvec4* __restrict__ x,
    const float* __restrict__ momentum,
    const float* __restrict__ lamb,
    const float* __restrict__ thresholds,
    fvec4*       __restrict__ out)
{
    // Disable FMA contraction: spike threshold is exact-compare against the
    // numpy fp32 reference; contraction changes rounding of the m-update and
    // can flip spikes at the boundary (error 1.0).
#pragma clang fp contract(off)

    const int tid = blockIdx.x * blockDim.x + threadIdx.x;   // 0 .. B*F4-1
    const int b   = tid >> 11;            // tid / F4   (F4 == 2048)
    const int f4  = tid & (F4 - 1);

    const float mt  = momentum[0];
    const float omt = 1.0f - mt;
    const float lb  = lamb[0];
    const float olb = 1.0f - lb;
    const float th  = thresholds[0];

    int idx = b * (T * F4) + f4;   // float4 index; stride F4 per timestep

    float u0 = 0.0f, u1 = 0.0f, u2 = 0.0f, u3 = 0.0f;
    float m0 = 0.0f, m1 = 0.0f, m2 = 0.0f, m3 = 0.0f;

    // 2-deep software pipeline with nontemporal (cache-bypassing) loads.
    fvec4 x0 = __builtin_nontemporal_load(&x[idx]);          // t = 0
    fvec4 x1 = __builtin_nontemporal_load(&x[idx + F4]);     // t = 1

#pragma unroll 2
    for (int t = 0; t < T; ++t) {
        // Prefetch t+2 (clamped on the tail; value discarded there).
        const int poff = (t + 2 < T) ? 2 * F4 : 0;
        const fvec4 xn = __builtin_nontemporal_load(&x[idx + poff]);

        fvec4 sv;

        // component 0
        {
            const float u  = u0 * 0.5f + x0.x;
            const float s  = ((u - th) >= 0.0f) ? 1.0f : 0.0f;
            const float a  = mt * m0;
            const float bq = omt * (u - u0);
            m0 = a + bq;
            u0 = (u * lb + m0 * olb) * (1.0f - s);
            sv.x = s;
        }
        // component 1
        {
            const float u  = u1 * 0.5f + x0.y;
            const float s  = ((u - th) >= 0.0f) ? 1.0f : 0.0f;
            const float a  = mt * m1;
            const float bq = omt * (u - u1);
            m1 = a + bq;
            u1 = (u * lb + m1 * olb) * (1.0f - s);
            sv.y = s;
        }
        // component 2
        {
            const float u  = u2 * 0.5f + x0.z;
            const float s  = ((u - th) >= 0.0f) ? 1.0f : 0.0f;
            const float a  = mt * m2;
            const float bq = omt * (u - u2);
            m2 = a + bq;
            u2 = (u * lb + m2 * olb) * (1.0f - s);
            sv.z = s;
        }
        // component 3
        {
            const float u  = u3 * 0.5f + x0.w;
            const float s  = ((u - th) >= 0.0f) ? 1.0f : 0.0f;
            const float a  = mt * m3;
            const float bq = omt * (u - u3);
            m3 = a + bq;
            u3 = (u * lb + m3 * olb) * (1.0f - s);
            sv.w = s;
        }

        __builtin_nontemporal_store(sv, &out[idx]);
        idx += F4;
        x0 = x1;
        x1 = xn;
    }
}

extern "C" void kernel_launch(void* const* d_in, const int* in_sizes, int n_in,
                              void* d_out, int out_size, void* d_ws, size_t ws_size,
                              hipStream_t stream) {
    const fvec4* x   = (const fvec4*)d_in[0];
    const float* mom = (const float*)d_in[1];
    const float* lmb = (const float*)d_in[2];
    const float* thr = (const float*)d_in[3];
    fvec4* out = (fvec4*)d_out;

    const int n_threads = B * F4;          // 131072
    const int block = 256;
    const int grid = n_threads / block;    // 512
    lif_fwd_kernel<<<grid, block, 0, stream>>>(x, mom, lmb, thr, out);
}